// Round 19
// baseline (847.069 us; speedup 1.0000x reference)
//
#include <hip/hip_runtime.h>
#include <hip/hip_bf16.h>
#include <hip/hip_cooperative_groups.h>
#include <math.h>

namespace cg = cooperative_groups;

#define C 256
#define NROWS (64*56*56)   // 200704
#define EPSV 0.001f
#define TRI(i) (((i)*((i)+1))>>1)
#define NBLK 224           // k_cov blocks
#define FGRID 64           // k_factco blocks

typedef __attribute__((ext_vector_type(8))) short bf16x8;
typedef __attribute__((ext_vector_type(4))) float f32x4;
typedef __attribute__((ext_vector_type(4))) unsigned short u16x4;
typedef __attribute__((ext_vector_type(8))) unsigned short u16x8;
#define MFMA16 __builtin_amdgcn_mfma_f32_16x16x32_bf16

// padded packed-lower-triangle layout: row i starts at PAD(i), rows rounded to 4 floats
__device__ __forceinline__ int PAD(int i) {
    int a = i >> 2, b = i & 3;
    return ((a + 1) * (2 * a + b)) << 2;
}

__device__ __forceinline__ float bcastf(float v, int l) {
    return __int_as_float(__builtin_amdgcn_readlane(__float_as_int(v), l));
}

__device__ __forceinline__ void split2(float v0, float v1, unsigned& hi, unsigned& lo) {
    unsigned b0 = __float_as_uint(v0), b1 = __float_as_uint(v1);
    hi = (b0 >> 16) | (b1 & 0xFFFF0000u);
    float l0 = v0 - __uint_as_float(b0 & 0xFFFF0000u);
    float l1 = v1 - __uint_as_float(b1 & 0xFFFF0000u);
    lo = (__float_as_uint(l0) >> 16) | (__float_as_uint(l1) & 0xFFFF0000u);
}

// ws layout (floats):
//  [0,256)              : channel sums
//  [256,512)            : biasacc
//  [512,33792)          : Lg  (cov -> diag 64-blocks := Dinv64)
//  [33792,7832576)      : P   = per-block cov partials [224][8][17][256]
//  [7832576,+32768)     : Wphi
//  [7865344,+32768)     : Wplo
//  [7898112,+49152)     : Pan = persisted 64-panels [3][256][64]

// ---------------- K2: S = X^T X via bf16-split MFMA, partials to P ----------------
template<int W>
__device__ __forceinline__ void cov_step(f32x4* acc, const unsigned* lh, const unsigned* ll,
                                         int m, int kg) {
    constexpr int R0 = W, R1 = 15 - W;
    constexpr int O1 = W + 1;
    bf16x8 ah[2], al[2];
    {
        int r0 = R0 * 16 + m, r1 = R1 * 16 + m;
        int o0 = r0 * 20 + ((kg ^ ((r0 >> 3) & 3)) << 2);
        int o1 = r1 * 20 + ((kg ^ ((r1 >> 3) & 3)) << 2);
        ah[0] = *(const bf16x8*)&lh[o0]; al[0] = *(const bf16x8*)&ll[o0];
        ah[1] = *(const bf16x8*)&lh[o1]; al[1] = *(const bf16x8*)&ll[o1];
    }
#pragma unroll
    for (int c = 0; c <= R1; ++c) {
        int rb = c * 16 + m;
        int ob = rb * 20 + ((kg ^ ((rb >> 3) & 3)) << 2);
        bf16x8 bh = *(const bf16x8*)&lh[ob];
        bf16x8 bl = *(const bf16x8*)&ll[ob];
        if (c <= R0) {
            acc[c] = MFMA16(ah[0], bh, acc[c], 0, 0, 0);
            acc[c] = MFMA16(ah[0], bl, acc[c], 0, 0, 0);
            acc[c] = MFMA16(al[0], bh, acc[c], 0, 0, 0);
        }
        {
            acc[O1 + c] = MFMA16(ah[1], bh, acc[O1 + c], 0, 0, 0);
            acc[O1 + c] = MFMA16(ah[1], bl, acc[O1 + c], 0, 0, 0);
            acc[O1 + c] = MFMA16(al[1], bh, acc[O1 + c], 0, 0, 0);
        }
    }
}

__global__ __launch_bounds__(512, 4) void k_cov(const float* __restrict__ x,
                                                float* __restrict__ P,
                                                float* __restrict__ sums) {
    __shared__ unsigned lh[256 * 20];
    __shared__ unsigned ll_[256 * 20];
    int tid = threadIdx.x, wave = tid >> 6, lane = tid & 63;
    int m = lane & 15, kg = lane >> 4;
    int ch = tid & 255, half = tid >> 8;
    const float* xc = x + (size_t)blockIdx.x * 896 * 256 + ch;
    f32x4 acc[17];
#pragma unroll
    for (int t = 0; t < 17; ++t) acc[t] = 0.f;
    float colsum = 0.f;
    int swkey = (ch >> 3) & 3;

    for (int it = 0; it < 28; ++it) {
        __syncthreads();
        const float* xr = xc + it * 32 * 256;
#pragma unroll
        for (int j = 0; j < 8; ++j) {
            int rp = half * 8 + j;
            float v0 = xr[(2 * rp) * 256];
            float v1 = xr[(2 * rp + 1) * 256];
            colsum += v0 + v1;
            unsigned h, l;
            split2(v0, v1, h, l);
            int idx = ch * 20 + ((((rp >> 2) ^ swkey) << 2) | (rp & 3));
            lh[idx] = h;
            ll_[idx] = l;
        }
        __syncthreads();
        switch (wave) {
            case 0: cov_step<0>(acc, lh, ll_, m, kg); break;
            case 1: cov_step<1>(acc, lh, ll_, m, kg); break;
            case 2: cov_step<2>(acc, lh, ll_, m, kg); break;
            case 3: cov_step<3>(acc, lh, ll_, m, kg); break;
            case 4: cov_step<4>(acc, lh, ll_, m, kg); break;
            case 5: cov_step<5>(acc, lh, ll_, m, kg); break;
            case 6: cov_step<6>(acc, lh, ll_, m, kg); break;
            default: cov_step<7>(acc, lh, ll_, m, kg); break;
        }
    }
    atomicAdd(&sums[ch], colsum);
    float* Pb = P + ((size_t)(blockIdx.x * 8 + wave) * 17) * 256;
#pragma unroll
    for (int t = 0; t < 17; ++t)
        *(f32x4*)&Pb[t * 256 + lane * 4] = acc[t];
}

// ---------------- register-wave 32x32 factor + triangular inverse ----------------
__device__ void regdiag32(const float* __restrict__ F, int fs,
                          float* __restrict__ G, int tid) {
    if (tid >= 64) return;
    int col = tid & 31;
    float a[32];
#pragma unroll
    for (int i = 0; i < 32; ++i) {
        int ii = (i >= col) ? i : col;
        int jj = (i >= col) ? col : i;
        a[i] = F[ii * fs + jj];
    }
    float drec = 0.f;
#pragma unroll
    for (int k = 0; k < 32; ++k) {
        float akk = bcastf(a[k], k);
        float rinv = rsqrtf(akk);
        float myl = a[k] * rinv;
        bool up = (col > k);
#pragma unroll
        for (int i = k + 1; i < 32; ++i) {
            float lik = bcastf(a[i], k) * rinv;
            if (up) a[i] -= lik * myl;
            if (col == k) a[i] = lik;
        }
        if (col == k) { a[k] = akk * rinv; drec = rinv; }
    }
    float xv[32];
#pragma unroll
    for (int i = 0; i < 32; ++i) xv[i] = (col == i) ? 1.f : 0.f;
#pragma unroll
    for (int i = 0; i < 32; ++i) {
        float di = bcastf(drec, i);
        float xi = xv[i] * di;
        xv[i] = xi;
#pragma unroll
        for (int j = i + 1; j < 32; ++j) {
            float lji = bcastf(a[j], i);
            xv[j] -= lji * xi;
        }
    }
    if (tid < 32) {
#pragma unroll
        for (int i = 0; i < 32; ++i)
            if (i >= col) G[i * 36 + col] = xv[i];
    }
}

// ---------------- in-block 64x64 factor: writes Dinv64 (lower) into Lg diag block ----------------
__device__ void factor64(float* __restrict__ Lg, int k0, int tid,
                         float* __restrict__ F,    // 64*68
                         float* __restrict__ G1,   // 32*36
                         float* __restrict__ G2,   // 32*36
                         float* __restrict__ M) {  // 32*36
    for (int u = tid; u < 4096; u += 256) {
        int r = u >> 6, c = u & 63;
        F[r * 68 + c] = (c <= r) ? Lg[PAD(k0 + r) + k0 + c] : 0.f;
    }
    for (int u = tid; u < 1152; u += 256) { G1[u] = 0.f; G2[u] = 0.f; M[u] = 0.f; }
    __syncthreads();
    regdiag32(F, 68, G1, tid);                       // A = inv(L11)
    __syncthreads();
    int tr = (tid >> 4) * 2, tc = (tid & 15) * 2;
    // L21 = A21 * A^T
    {
        float p00 = 0, p01 = 0, p10 = 0, p11 = 0;
#pragma unroll 8
        for (int k = 0; k < 32; ++k) {
            float f0 = F[(32 + tr) * 68 + k], f1 = F[(33 + tr) * 68 + k];
            float g0 = G1[tc * 36 + k],       g1 = G1[(tc + 1) * 36 + k];
            p00 += f0 * g0; p01 += f0 * g1;
            p10 += f1 * g0; p11 += f1 * g1;
        }
        __syncthreads();
        F[(32 + tr) * 68 + tc] = p00; F[(32 + tr) * 68 + tc + 1] = p01;
        F[(33 + tr) * 68 + tc] = p10; F[(33 + tr) * 68 + tc + 1] = p11;
    }
    __syncthreads();
    // A22 -= L21 L21^T  (lower mask)
    {
        float t00 = 0, t01 = 0, t10 = 0, t11 = 0;
#pragma unroll 8
        for (int k = 0; k < 32; ++k) {
            float a0 = F[(32 + tr) * 68 + k], a1 = F[(33 + tr) * 68 + k];
            float b0 = F[(32 + tc) * 68 + k], b1 = F[(33 + tc) * 68 + k];
            t00 += a0 * b0; t01 += a0 * b1;
            t10 += a1 * b0; t11 += a1 * b1;
        }
        if (tc     <= tr    ) F[(32 + tr) * 68 + 32 + tc]     -= t00;
        if (tc + 1 <= tr    ) F[(32 + tr) * 68 + 32 + tc + 1] -= t01;
        if (tc     <= tr + 1) F[(33 + tr) * 68 + 32 + tc]     -= t10;
        if (tc + 1 <= tr + 1) F[(33 + tr) * 68 + 32 + tc + 1] -= t11;
    }
    __syncthreads();
    regdiag32(&F[32 * 68 + 32], 68, G2, tid);        // B = inv(L22)
    __syncthreads();
    // M = L21 * A
    {
        float m00 = 0, m01 = 0, m10 = 0, m11 = 0;
#pragma unroll 8
        for (int k = 0; k < 32; ++k) {
            float l0 = F[(32 + tr) * 68 + k], l1 = F[(33 + tr) * 68 + k];
            float a0 = G1[k * 36 + tc],       a1 = G1[k * 36 + tc + 1];
            m00 += l0 * a0; m01 += l0 * a1;
            m10 += l1 * a0; m11 += l1 * a1;
        }
        M[tr * 36 + tc] = m00;       M[tr * 36 + tc + 1] = m01;
        M[(tr + 1) * 36 + tc] = m10; M[(tr + 1) * 36 + tc + 1] = m11;
    }
    __syncthreads();
    // C = -B * M ; write C
    {
        float c00 = 0, c01 = 0, c10 = 0, c11 = 0;
#pragma unroll 8
        for (int q = 0; q < 32; ++q) {
            float b0 = G2[tr * 36 + q], b1 = G2[(tr + 1) * 36 + q];
            float m0 = M[q * 36 + tc], m1 = M[q * 36 + tc + 1];
            c00 += b0 * m0; c01 += b0 * m1;
            c10 += b1 * m0; c11 += b1 * m1;
        }
        Lg[PAD(k0 + 32 + tr) + k0 + tc]     = -c00;
        Lg[PAD(k0 + 32 + tr) + k0 + tc + 1] = -c01;
        Lg[PAD(k0 + 33 + tr) + k0 + tc]     = -c10;
        Lg[PAD(k0 + 33 + tr) + k0 + tc + 1] = -c11;
    }
    // A, B (lower) -> Lg
    for (int u = tid; u < 1024; u += 256) {
        int i = u >> 5, j = u & 31;
        if (j <= i) {
            Lg[PAD(k0 + i) + k0 + j]           = G1[i * 36 + j];
            Lg[PAD(k0 + 32 + i) + k0 + 32 + j] = G2[i * 36 + j];
        }
    }
}

// ---------------- init chunk: sum P partials -> covariance entries ----------------
__device__ void init_chunk(const float* __restrict__ P, const float* __restrict__ sums,
                           float* __restrict__ Lg, int chunk, int tid) {
    int W = chunk / 17, t = chunk % 17;
    int R  = (t <= W) ? W : 15 - W;
    int tj = (t <= W) ? t : t - W - 1;
    int lane = tid >> 2, q = tid & 3;
    int kg = lane >> 4, m = lane & 15;
    int i = R * 16 + kg * 4 + q;
    int j = tj * 16 + m;
    float s = 0.f;
    const float* p = P + (size_t)chunk * 256 + tid;
#pragma unroll 4
    for (int b = 0; b < NBLK; ++b)
        s += p[(size_t)b * 8 * 17 * 256];
    if (j > i) return;
    const float scale = (1.f - EPSV) / ((float)NROWS - 1.f);
    float v = (s - sums[i] * sums[j] * (1.f / (float)NROWS)) * scale;
    if (i == j) v += EPSV;
    Lg[PAD(i) + j] = v;
}

// ---------------- K3a: cooperative init + 64-panel Cholesky (LDS 52 KB) ----------------
__global__ __launch_bounds__(256) void k_factco(const float* __restrict__ P,
                                                const float* __restrict__ sums,
                                                float* __restrict__ Lg,
                                                float* __restrict__ Pan) {
    cg::grid_group grid = cg::this_grid();
    __shared__ __align__(16) float SH[13056];   // 52.2 KB (< 64 KB coop limit)
    int tid = threadIdx.x, bid = blockIdx.x;

    // ---- phase 0: init covariance; block 0 owns first 64x64 diag, then factors it ----
    if (bid == 0) {
        for (int W = 0; W < 4; ++W)
            for (int t = 0; t <= W; ++t)
                init_chunk(P, sums, Lg, W * 17 + t, tid);
    }
    for (int chunk = bid; chunk < 136; chunk += FGRID) {
        int W = chunk / 17, t = chunk % 17;
        if (W < 4 && t <= W) continue;           // handled by block 0
        init_chunk(P, sums, Lg, chunk, tid);
    }
    if (bid == 0) {
        __syncthreads();
        factor64(Lg, 0, tid, SH, SH + 4352, SH + 5504, SH + 6656);
    }
    grid.sync();

    // ---- 64-panel chain: 3 phases, redundant panel per pair, Pa/Pb via registers ----
    for (int kb = 0; kb < 3; ++kb) {
        int npairs = TRI(3 - kb);
        if (bid < npairs) {
            float* DS = SH;            // 64*68  Dinv64(kb), zero upper
            float* Ar = SH + 4352;     // 64*68  raw rows ib2 -> Pa
            float* Br = SH + 8704;     // 64*68  raw rows jb2 -> Pb
            int p = bid, a2 = 0;
            while (TRI(a2 + 1) <= p) ++a2;
            int b2 = p - TRI(a2);
            int ib2 = kb + 1 + a2, jb2 = kb + 1 + b2;
            bool dg = (ib2 == jb2);
            int k0 = kb * 64;

            for (int u = tid; u < 1024; u += 256) {
                int r = u >> 4, cq = (u & 15) * 4;
                const float* drow = &Lg[PAD(k0 + r) + k0];
                float4 dv;
                dv.x = (cq     <= r) ? drow[cq]     : 0.f;
                dv.y = (cq + 1 <= r) ? drow[cq + 1] : 0.f;
                dv.z = (cq + 2 <= r) ? drow[cq + 2] : 0.f;
                dv.w = (cq + 3 <= r) ? drow[cq + 3] : 0.f;
                *(float4*)&DS[r * 68 + cq] = dv;
                *(float4*)&Ar[r * 68 + cq] = *(const float4*)&Lg[PAD(ib2 * 64 + r) + k0 + cq];
                *(float4*)&Br[r * 68 + cq] = *(const float4*)&Lg[PAD(jb2 * 64 + r) + k0 + cq];
            }
            __syncthreads();

            int tr = (tid >> 4) * 4, tc = (tid & 15) * 4;
            // registers: pa = Ar*DS^T, pb = Br*DS^T
            float pa[4][4], pb[4][4];
#pragma unroll
            for (int rr = 0; rr < 4; ++rr)
#pragma unroll
                for (int cc = 0; cc < 4; ++cc) { pa[rr][cc] = 0.f; pb[rr][cc] = 0.f; }
#pragma unroll 4
            for (int k4 = 0; k4 < 64; k4 += 4) {
                float4 d0 = *(const float4*)&DS[tc * 68 + k4];
                float4 d1 = *(const float4*)&DS[(tc + 1) * 68 + k4];
                float4 d2 = *(const float4*)&DS[(tc + 2) * 68 + k4];
                float4 d3 = *(const float4*)&DS[(tc + 3) * 68 + k4];
#pragma unroll
                for (int rr = 0; rr < 4; ++rr) {
                    float4 av = *(const float4*)&Ar[(tr + rr) * 68 + k4];
                    pa[rr][0] += av.x*d0.x + av.y*d0.y + av.z*d0.z + av.w*d0.w;
                    pa[rr][1] += av.x*d1.x + av.y*d1.y + av.z*d1.z + av.w*d1.w;
                    pa[rr][2] += av.x*d2.x + av.y*d2.y + av.z*d2.z + av.w*d2.w;
                    pa[rr][3] += av.x*d3.x + av.y*d3.y + av.z*d3.z + av.w*d3.w;
                    float4 bv = *(const float4*)&Br[(tr + rr) * 68 + k4];
                    pb[rr][0] += bv.x*d0.x + bv.y*d0.y + bv.z*d0.z + bv.w*d0.w;
                    pb[rr][1] += bv.x*d1.x + bv.y*d1.y + bv.z*d1.z + bv.w*d1.w;
                    pb[rr][2] += bv.x*d2.x + bv.y*d2.y + bv.z*d2.z + bv.w*d2.w;
                    pb[rr][3] += bv.x*d3.x + bv.y*d3.y + bv.z*d3.z + bv.w*d3.w;
                }
            }
            __syncthreads();   // all raw reads done; safe to overwrite Ar/Br
#pragma unroll
            for (int rr = 0; rr < 4; ++rr) {
                float4 va; va.x = pa[rr][0]; va.y = pa[rr][1]; va.z = pa[rr][2]; va.w = pa[rr][3];
                float4 vb; vb.x = pb[rr][0]; vb.y = pb[rr][1]; vb.z = pb[rr][2]; vb.w = pb[rr][3];
                *(float4*)&Ar[(tr + rr) * 68 + tc] = va;   // Ar := Pa
                *(float4*)&Br[(tr + rr) * 68 + tc] = vb;   // Br := Pb
            }
            __syncthreads();

            if (dg) {
                for (int u = tid; u < 1024; u += 256) {
                    int r = u >> 4, cq = (u & 15) * 4;
                    *(float4*)&Pan[((size_t)kb * 256 + ib2 * 64 + r) * 64 + cq] =
                        *(const float4*)&Ar[r * 68 + cq];
                }
            }

            // trail: Lg(ib2,jb2) -= Pa * Pb^T
            {
                float t4[4][4];
#pragma unroll
                for (int rr = 0; rr < 4; ++rr)
#pragma unroll
                    for (int cc = 0; cc < 4; ++cc) t4[rr][cc] = 0.f;
#pragma unroll 4
                for (int k4 = 0; k4 < 64; k4 += 4) {
                    float4 b0 = *(const float4*)&Br[tc * 68 + k4];
                    float4 b1 = *(const float4*)&Br[(tc + 1) * 68 + k4];
                    float4 b2 = *(const float4*)&Br[(tc + 2) * 68 + k4];
                    float4 b3 = *(const float4*)&Br[(tc + 3) * 68 + k4];
#pragma unroll
                    for (int rr = 0; rr < 4; ++rr) {
                        float4 av = *(const float4*)&Ar[(tr + rr) * 68 + k4];
                        t4[rr][0] += av.x*b0.x + av.y*b0.y + av.z*b0.z + av.w*b0.w;
                        t4[rr][1] += av.x*b1.x + av.y*b1.y + av.z*b1.z + av.w*b1.w;
                        t4[rr][2] += av.x*b2.x + av.y*b2.y + av.z*b2.z + av.w*b2.w;
                        t4[rr][3] += av.x*b3.x + av.y*b3.y + av.z*b3.z + av.w*b3.w;
                    }
                }
#pragma unroll
                for (int rr = 0; rr < 4; ++rr) {
                    int gi = ib2 * 64 + tr + rr;
#pragma unroll
                    for (int cc = 0; cc < 4; ++cc) {
                        int gj = jb2 * 64 + tc + cc;
                        if (!dg || gj <= gi) Lg[PAD(gi) + gj] -= t4[rr][cc];
                    }
                }
            }

            if (bid == 0) {
                __syncthreads();
                factor64(Lg, (kb + 1) * 64, tid, SH, SH + 4352, SH + 5504, SH + 6656);
            }
        }
        if (kb < 2) grid.sync();
    }
}

// ---------------- K3b: blocked inverse (4 col-blocks of 64) + bf16 pack (regular launch) ----------------
__global__ __launch_bounds__(256) void k_inv64(const float* __restrict__ Lg,
                                               const float* __restrict__ Pan,
                                               const float* __restrict__ sums,
                                               const float* __restrict__ gamma,
                                               unsigned short* __restrict__ Wphi,
                                               unsigned short* __restrict__ Wplo,
                                               float* __restrict__ biasacc) {
    __shared__ __align__(16) float Wcol[17408];   // [256][68]
    __shared__ __align__(16) float Ls[4352];      // [64][68]
    __shared__ __align__(16) float Tst[4352];     // [64][68]
    int jbb = blockIdx.x, tid = threadIdx.x;
    int j0 = jbb * 64;

    for (int u = tid; u < 1024; u += 256) {
        int r = u >> 4, cq = (u & 15) * 4;
        const float* row = &Lg[PAD(j0 + r) + j0];
        float4 v;
        v.x = (cq     <= r) ? row[cq]     : 0.f;
        v.y = (cq + 1 <= r) ? row[cq + 1] : 0.f;
        v.z = (cq + 2 <= r) ? row[cq + 2] : 0.f;
        v.w = (cq + 3 <= r) ? row[cq + 3] : 0.f;
        *(float4*)&Wcol[(j0 + r) * 68 + cq] = v;
    }
    __syncthreads();

    int tr = (tid >> 4) * 4, tc = (tid & 15) * 4;
    for (int ib = jbb + 1; ib < 4; ++ib) {
        int i0 = ib * 64;
        float t4[4][4];
#pragma unroll
        for (int rr = 0; rr < 4; ++rr)
#pragma unroll
            for (int cc = 0; cc < 4; ++cc) t4[rr][cc] = 0.f;
        for (int kb = jbb; kb < ib; ++kb) {
            __syncthreads();
            for (int u = tid; u < 1024; u += 256) {
                int r = u >> 4, cq = (u & 15) * 4;
                *(float4*)&Ls[r * 68 + cq] =
                    *(const float4*)&Pan[((size_t)kb * 256 + i0 + r) * 64 + cq];
            }
            __syncthreads();
            int kw = kb * 64;
#pragma unroll 4
            for (int q4 = 0; q4 < 64; q4 += 4) {
                float4 w0 = *(const float4*)&Wcol[(kw + q4)     * 68 + tc];
                float4 w1 = *(const float4*)&Wcol[(kw + q4 + 1) * 68 + tc];
                float4 w2 = *(const float4*)&Wcol[(kw + q4 + 2) * 68 + tc];
                float4 w3 = *(const float4*)&Wcol[(kw + q4 + 3) * 68 + tc];
#pragma unroll
                for (int rr = 0; rr < 4; ++rr) {
                    float4 lv = *(const float4*)&Ls[(tr + rr) * 68 + q4];
                    t4[rr][0] += lv.x*w0.x + lv.y*w1.x + lv.z*w2.x + lv.w*w3.x;
                    t4[rr][1] += lv.x*w0.y + lv.y*w1.y + lv.z*w2.y + lv.w*w3.y;
                    t4[rr][2] += lv.x*w0.z + lv.y*w1.z + lv.z*w2.z + lv.w*w3.z;
                    t4[rr][3] += lv.x*w0.w + lv.y*w1.w + lv.z*w2.w + lv.w*w3.w;
                }
            }
        }
        __syncthreads();
#pragma unroll
        for (int rr = 0; rr < 4; ++rr) {
            float4 v; v.x = t4[rr][0]; v.y = t4[rr][1]; v.z = t4[rr][2]; v.w = t4[rr][3];
            *(float4*)&Tst[(tr + rr) * 68 + tc] = v;
        }
        for (int u = tid; u < 1024; u += 256) {
            int r = u >> 4, cq = (u & 15) * 4;
            const float* row = &Lg[PAD(i0 + r) + i0];
            float4 v;
            v.x = (cq     <= r) ? row[cq]     : 0.f;
            v.y = (cq + 1 <= r) ? row[cq + 1] : 0.f;
            v.z = (cq + 2 <= r) ? row[cq + 2] : 0.f;
            v.w = (cq + 3 <= r) ? row[cq + 3] : 0.f;
            *(float4*)&Ls[r * 68 + cq] = v;   // Dinv64(ib)
        }
        __syncthreads();
        float w4[4][4];
#pragma unroll
        for (int rr = 0; rr < 4; ++rr)
#pragma unroll
            for (int cc = 0; cc < 4; ++cc) w4[rr][cc] = 0.f;
#pragma unroll 4
        for (int q4 = 0; q4 < 64; q4 += 4) {
            float4 t0 = *(const float4*)&Tst[q4       * 68 + tc];
            float4 t1 = *(const float4*)&Tst[(q4 + 1) * 68 + tc];
            float4 t2 = *(const float4*)&Tst[(q4 + 2) * 68 + tc];
            float4 t3 = *(const float4*)&Tst[(q4 + 3) * 68 + tc];
#pragma unroll
            for (int rr = 0; rr < 4; ++rr) {
                float4 lv = *(const float4*)&Ls[(tr + rr) * 68 + q4];
                w4[rr][0] += lv.x*t0.x + lv.y*t1.x + lv.z*t2.x + lv.w*t3.x;
                w4[rr][1] += lv.x*t0.y + lv.y*t1.y + lv.z*t2.y + lv.w*t3.y;
                w4[rr][2] += lv.x*t0.z + lv.y*t1.z + lv.z*t2.z + lv.w*t3.z;
                w4[rr][3] += lv.x*t0.w + lv.y*t1.w + lv.z*t2.w + lv.w*t3.w;
            }
        }
#pragma unroll
        for (int rr = 0; rr < 4; ++rr) {
            float4 v; v.x = -w4[rr][0]; v.y = -w4[rr][1]; v.z = -w4[rr][2]; v.w = -w4[rr][3];
            *(float4*)&Wcol[(i0 + tr + rr) * 68 + tc] = v;
        }
        __syncthreads();
    }

    {
        int r = tid;
        if (r >= j0) {
            float s = 0.f;
#pragma unroll 8
            for (int c = 0; c < 64; ++c)
                s += Wcol[r * 68 + c] * sums[j0 + c];
            atomicAdd(&biasacc[r], s * (1.f / (float)NROWS));
        }
    }
    for (int pi = tid; pi < 2048; pi += 256) {
        int kcg2 = pi >> 10, idx = pi & 1023;
        int jt = idx >> 6, l = idx & 63;
        int row = jt * 16 + (l & 15);
        int cb = kcg2 * 32 + (l >> 4) * 8;
        int kcg = jbb * 2 + kcg2;
        float g = (row >= j0) ? gamma[row] : 0.f;
        u16x4 h0, h1, lo0, lo1;
#pragma unroll
        for (int j = 0; j < 8; ++j) {
            float v = (row >= j0) ? g * Wcol[row * 68 + cb + j] : 0.f;
            unsigned b = __float_as_uint(v);
            unsigned short hi = (unsigned short)(b >> 16);
            float lf = v - __uint_as_float(b & 0xFFFF0000u);
            unsigned short lo = (unsigned short)(__float_as_uint(lf) >> 16);
            if (j < 4) { h0[j] = hi; lo0[j] = lo; }
            else       { h1[j - 4] = hi; lo1[j - 4] = lo; }
        }
        size_t base = ((size_t)(jt * 8 + kcg) * 64 + l) * 8;
        *(u16x4*)&Wphi[base]     = h0;
        *(u16x4*)&Wphi[base + 4] = h1;
        *(u16x4*)&Wplo[base]     = lo0;
        *(u16x4*)&Wplo[base + 4] = lo1;
    }
}

// ---------------- K4: out = bf16(x) * Wg^T + bias; B staged in LDS per kcg ----------------
__global__ __launch_bounds__(512) void k_apply(const float* __restrict__ x,
                                               const unsigned short* __restrict__ Wphi,
                                               const unsigned short* __restrict__ Wplo,
                                               const float* __restrict__ beta,
                                               const float* __restrict__ gamma,
                                               const float* __restrict__ biasacc,
                                               float* __restrict__ out) {
    __shared__ unsigned short Bh[8192];
    __shared__ unsigned short Bl[8192];
    int tid = threadIdx.x, wave = tid >> 6, lane = tid & 63;
    int m = lane & 15, kg = lane >> 4;
    size_t rbase = (size_t)blockIdx.x * 128 + wave * 16;
    const float* xr = x + (rbase + m) * 256;

    f32x4 acc[16];
#pragma unroll
    for (int t = 0; t < 16; ++t) acc[t] = 0.f;

#pragma unroll
    for (int kcg = 0; kcg < 8; ++kcg) {
        __syncthreads();
#pragma unroll
        for (int v = tid; v < 1024; v += 512) {
            int jt = v >> 6, off = (v & 63) * 8;
            size_t src = (size_t)(jt * 8 + kcg) * 512 + off;
            int dst = jt * 512 + off;
            *(u16x8*)&Bh[dst] = *(const u16x8*)&Wphi[src];
            *(u16x8*)&Bl[dst] = *(const u16x8*)&Wplo[src];
        }
        f32x4 a0 = *(const f32x4*)&xr[kcg * 32 + kg * 8];
        f32x4 a1 = *(const f32x4*)&xr[kcg * 32 + kg * 8 + 4];
        bf16x8 ah;
#pragma unroll
        for (int e = 0; e < 4; ++e) {
            unsigned b0 = __float_as_uint(a0[e]);
            b0 += 0x7FFFu + ((b0 >> 16) & 1u);
            ah[e] = (short)(b0 >> 16);
            unsigned b1 = __float_as_uint(a1[e]);
            b1 += 0x7FFFu + ((b1 >> 16) & 1u);
            ah[4 + e] = (short)(b1 >> 16);
        }
        __syncthreads();
#pragma unroll
        for (int jt = 0; jt < 16; ++jt) {
            bf16x8 bh = *(const bf16x8*)&Bh[jt * 512 + lane * 8];
            bf16x8 bl = *(const bf16x8*)&Bl[jt * 512 + lane * 8];
            acc[jt] = MFMA16(ah, bh, acc[jt], 0, 0, 0);
            acc[jt] = MFMA16(ah, bl, acc[jt], 0, 0, 0);
        }
    }

#pragma unroll
    for (int jt = 0; jt < 16; ++jt) {
        int j = jt * 16 + m;
        float bb = beta[j] - gamma[j] * biasacc[j];
#pragma unroll
        for (int q = 0; q < 4; ++q)
            out[(rbase + kg * 4 + q) * 256 + j] = acc[jt][q] + bb;
    }
}

extern "C" void kernel_launch(void* const* d_in, const int* in_sizes, int n_in,
                              void* d_out, int out_size, void* d_ws, size_t ws_size,
                              hipStream_t stream) {
    const float* x     = (const float*)d_in[0];
    const float* gamma = (const float*)d_in[1];
    const float* beta  = (const float*)d_in[2];
    float* out  = (float*)d_out;
    float* ws   = (float*)d_ws;
    float* sums     = ws;                 // 256
    float* biasacc  = ws + 256;           // 256
    float* Lg       = ws + 512;           // 33280
    float* P        = ws + 33792;         // 224*8*17*256
    unsigned short* Wphi = (unsigned short*)(ws + 7832576);  // 65536 bf16
    unsigned short* Wplo = (unsigned short*)(ws + 7865344);  // 65536 bf16
    float* Pan      = ws + 7898112;       // 3*256*64 = 49152

    hipMemsetAsync(ws, 0, 512 * sizeof(float), stream);
    hipLaunchKernelGGL(k_cov, dim3(NBLK), dim3(512), 0, stream, x, P, sums);
    {
        void* args[] = { (void*)&P, (void*)&sums, (void*)&Lg, (void*)&Pan };
        hipLaunchCooperativeKernel((const void*)k_factco, dim3(FGRID), dim3(256),
                                   args, 0, stream);
    }
    hipLaunchKernelGGL(k_inv64, dim3(4), dim3(256), 0, stream, Lg, Pan, sums, gamma, Wphi, Wplo, biasacc);
    hipLaunchKernelGGL(k_apply, dim3(1568), dim3(512), 0, stream, x, Wphi, Wplo, beta, gamma, biasacc, out);
}